// Round 12
// baseline (126.051 us; speedup 1.0000x reference)
//
#include <hip/hip_runtime.h>
#include <hip/hip_bf16.h>

typedef __attribute__((ext_vector_type(4))) int i32x4;
typedef unsigned char u8;

// ---------------- gamma = mean(|W|) + 1e-6, deterministic two-stage ----------------

__global__ void kabs_partial(const float* __restrict__ W, double* __restrict__ part, int n) {
    __shared__ double sd[256];
    const int tid = threadIdx.x;
    double s = 0.0;
    for (int i = blockIdx.x * blockDim.x + tid; i < n; i += gridDim.x * blockDim.x)
        s += (double)fabsf(W[i]);
    sd[tid] = s;
    __syncthreads();
    for (int off = 128; off > 0; off >>= 1) {
        if (tid < off) sd[tid] += sd[tid + off];
        __syncthreads();
    }
    if (tid == 0) part[blockIdx.x] = sd[0];
}

__global__ void kgamma(const double* __restrict__ part, float* __restrict__ gout, int nelem) {
    __shared__ double sd[256];
    const int tid = threadIdx.x;
    double s = part[tid] + part[tid + 256] + part[tid + 512] + part[tid + 768];
    sd[tid] = s;
    __syncthreads();
    for (int off = 128; off > 0; off >>= 1) {
        if (tid < off) sd[tid] += sd[tid + off];
        __syncthreads();
    }
    if (tid == 0) gout[0] = (float)(sd[0] / (double)nelem) + 1e-6f;
}

// ---------------- quantizers: write i8 {-1,0,+1} ----------------

__device__ __forceinline__ unsigned int qw_b(float w, float g) {
    float t = fabsf(w) / g;
    unsigned int u = __float_as_uint(w);
    return (rintf(t) >= 1.0f) ? ((u >> 31) ? 0xFFu : 0x01u) : 0u;
}

__global__ void kquant_w(const float4* __restrict__ W4, unsigned int* __restrict__ Wq,
                         const float* __restrict__ gptr, int n4) {
    int i = blockIdx.x * blockDim.x + threadIdx.x;
    if (i >= n4) return;
    const float g = *gptr;
    float4 w = W4[i];
    Wq[i] = qw_b(w.x, g) | (qw_b(w.y, g) << 8) | (qw_b(w.z, g) << 16) | (qw_b(w.w, g) << 24);
}

__device__ __forceinline__ unsigned int sgn_b(float a) {
    unsigned int u = __float_as_uint(a);
    return (u & 0x7FFFFFFFu) ? ((u >> 31) ? 0xFFu : 0x01u) : 0u;
}
__device__ __forceinline__ unsigned int sgn4(float4 v) {
    return sgn_b(v.x) | (sgn_b(v.y) << 8) | (sgn_b(v.z) << 16) | (sgn_b(v.w) << 24);
}

__global__ void kquant_x(const float4* __restrict__ X4, uint4* __restrict__ Xq, size_t n16) {
    size_t i = (size_t)blockIdx.x * blockDim.x + threadIdx.x;
    if (i >= n16) return;
    uint4 o;
    o.x = sgn4(X4[4 * i]);
    o.y = sgn4(X4[4 * i + 1]);
    o.z = sgn4(X4[4 * i + 2]);
    o.w = sgn4(X4[4 * i + 3]);
    Xq[i] = o;
}

// ---------------- 256x256 2-phase-per-tile i8 MFMA GEMM (race-fixed calendar) ----------
// C[M][N] = A[M][K] * B[N][K]^T, A/B i8 {-1,0,+1}, acc i32 (exact), out f32.
// 8 waves (2M x 4N), per-wave 128x64; tile tau (K=128, 128B rows) in buf tau&1.
// Phase = {STAGE (calendar below); [VMC4 @ph2/ph4]; BARRIER; lgkm0+sched_barrier;
// setprio(1); 32 MFMA; setprio(0); tail ds_reads for next phase}.
//
// SAFETY INVARIANT (R11 bug fix): a region's restage must have >= 1 BARRIER between
// the last tail-read of that region and the stage issue. (Write issues post-barrier
// and lands ~300+ cyc later via global fetch; an already-enqueued ds_read ~120 cyc
// always completes first. Sep-0 — same window — is a real race, R11 absmax=228.)
// Windows: stage of phase p sits in [B(p-1), Bp); tail reads of phase r in [Br, Br+1).
// Calendar audit (stage window vs last-read window):
//   ph1 As11@kb1 (W0) vs prev-ph3 tail (W-1): B4p between  OK
//   ph1 Bs11@kb1 (W0) vs prev-ph2 tail (W-2): sep 2        OK
//   ph2 As00,Bs00@kb2 (W1) vs prev-ph4 tail (W0): B1 between OK
//   ph3 Bs01@kb2 (W2) vs prev-ph4 tail (W0): sep 2         OK
//   ph3 As01@kb2 (W2) vs ph1 tail (W1): B2 between         OK
//   ph4 As10,Bs10@kb3 (W3) vs ph2 tail (W2): B3 between    OK
// Ledger: 4 loads/phase. VMC4@ph2 certifies tile t+1 ({As10,Bs10}@prev-ph4 +
// {As11,Bs11}@ph1), youngest awaited load 1 phase (~1900cyc) old. VMC4@ph4 certifies
// tile t+2 ({As00,Bs00}@ph2 + {Bs01,As01}@ph3). Never vmcnt(0) in loop.
// Tail: kb clamps re-stage tile NT-1 into dead regions (count-exact); final cross-pair
// reads guarded by (t+2 < NT).

#define STAGE_HALF(SRC, DST, BASE_ROW, KB)                                                  \
    {                                                                                       \
        _Pragma("unroll")                                                                   \
        for (int l = 0; l < 2; ++l) {                                                       \
            const int r_ = l * 64 + srow;                                                   \
            const u8* g_ = (SRC) + (size_t)((BASE_ROW) + r_) * K + (KB) +                   \
                           (sec ^ ((r_ & 7) << 4));                                         \
            __builtin_amdgcn_global_load_lds(                                               \
                (const __attribute__((address_space(1))) unsigned int*)g_,                  \
                (__attribute__((address_space(3))) unsigned int*)&(DST)[r_][sec], 16, 0, 0);\
        }                                                                                   \
    }

#define BARRIER do { asm volatile("" ::: "memory"); __builtin_amdgcn_s_barrier(); \
                     asm volatile("" ::: "memory"); } while (0)
#define LGKM0   do { asm volatile("s_waitcnt lgkmcnt(0)" ::: "memory"); \
                     __builtin_amdgcn_sched_barrier(0); } while (0)
#define VMC4    asm volatile("s_waitcnt vmcnt(4)" ::: "memory")

#define DS_READ_A4(BUF, mb, dst)                                                            \
    {                                                                                       \
        _Pragma("unroll")                                                                   \
        for (int mi = 0; mi < 4; ++mi) {                                                    \
            const int m_ = (mb) + mi;                                                       \
            const int ra = wm * 64 + (m_ & 3) * 16 + lr;                                    \
            _Pragma("unroll")                                                               \
            for (int ks = 0; ks < 2; ++ks)                                                  \
                dst[mi][ks] = *(const i32x4*)&As[BUF][m_ >> 2][ra]                          \
                                  [(ks * 64 + lk16) ^ ((ra & 7) << 4)];                     \
        }                                                                                   \
    }

#define DS_READ_B(BUF)                                                                      \
    {                                                                                       \
        _Pragma("unroll")                                                                   \
        for (int n = 0; n < 4; ++n) {                                                       \
            const int rb = (wn & 1) * 64 + n * 16 + lr;                                     \
            _Pragma("unroll")                                                               \
            for (int ks = 0; ks < 2; ++ks)                                                  \
                bv[n][ks] = *(const i32x4*)&Bs[BUF][wn >> 1][rb]                            \
                                [(ks * 64 + lk16) ^ ((rb & 7) << 4)];                       \
        }                                                                                   \
    }

#define MFMA4(mb, AV)                                                                       \
    do {                                                                                    \
        __builtin_amdgcn_s_setprio(1);                                                      \
        _Pragma("unroll")                                                                   \
        for (int mi = 0; mi < 4; ++mi)                                                      \
            _Pragma("unroll")                                                               \
            for (int n = 0; n < 4; ++n)                                                     \
                _Pragma("unroll")                                                           \
                for (int ks = 0; ks < 2; ++ks)                                              \
                    acc[(mb) + mi][n] = __builtin_amdgcn_mfma_i32_16x16x64_i8(              \
                        AV[mi][ks], bv[n][ks], acc[(mb) + mi][n], 0, 0, 0);                 \
        __builtin_amdgcn_s_setprio(0);                                                      \
    } while (0)

__global__ __launch_bounds__(512, 2) void kgemm(const u8* __restrict__ A,
                                                const u8* __restrict__ B,
                                                float* __restrict__ C,
                                                int M, int N, int K) {
    __shared__ u8 As[2][2][128][128];
    __shared__ u8 Bs[2][2][128][128];

    const int tid = threadIdx.x;
    const int lane = tid & 63;
    const int wid = tid >> 6;      // 0..7
    const int wm = wid >> 2;       // 0..1  (M sub-block within each half)
    const int wn = wid & 3;        // 0..3  (N sub-block)

    // T1: XCD-aware block swizzle (grid % 8 == 0 here)
    int bid = blockIdx.x;
    const int nwg = gridDim.x;
    if ((nwg & 7) == 0) bid = (bid & 7) * (nwg >> 3) + (bid >> 3);
    const int nbn = N >> 8;
    const int bm = bid / nbn, bn = bid % nbn;
    const int row0 = bm << 8, col0 = bn << 8;

    const int lr = lane & 15;
    const int lk16 = (lane >> 4) * 16;   // byte offset of this lane-group's K-chunk

    // staging thread mapping: 512 threads cover 64 rows x 128 bytes per load instr
    const int srow = tid >> 3;           // 0..63
    const int sec  = (tid & 7) * 16;     // 16-byte chunk within the 128B row

    i32x4 acc[8][4] = {};
    const int NT = K >> 7;               // 16 tiles of K=128 (K % 256 == 0 guaranteed)

    // ---- prologue: tile0 (4 halves) + tile1's {As10,Bs10}; certify tile0; preload frags
    STAGE_HALF(B, Bs[0][0], col0, 0);
    STAGE_HALF(B, Bs[0][1], col0 + 128, 0);
    STAGE_HALF(A, As[0][0], row0, 0);
    STAGE_HALF(A, As[0][1], row0 + 128, 0);
    STAGE_HALF(A, As[1][0], row0, 128);
    STAGE_HALF(B, Bs[1][0], col0, 128);
    VMC4;                                 // drain tile0's 8, leave tile1's 4 in flight
    BARRIER;

    i32x4 bv[4][2], av0[4][2], av1[4][2];
    DS_READ_B(0);
    DS_READ_A4(0, 0, av0);

    for (int t = 0; t < NT; t += 2) {
        const int kb1 = (t + 1) << 7;
        const int kb2 = (t + 2 < NT ? t + 2 : NT - 1) << 7;
        const int kb3 = (t + 3 < NT ? t + 3 : NT - 1) << 7;

        // ph1: complete tile t+1 staging; MFMA m0-3 (t); tail: read m4-7 (t)
        STAGE_HALF(A, As[1][1], row0 + 128, kb1);
        STAGE_HALF(B, Bs[1][1], col0 + 128, kb1);
        BARRIER; LGKM0;
        MFMA4(0, av0);
        DS_READ_A4(0, 4, av1);
        // ph2: certify tile t+1; MFMA m4-7 (t); tail: read B + m0-3 (t+1)
        STAGE_HALF(A, As[0][0], row0, kb2);
        STAGE_HALF(B, Bs[0][0], col0, kb2);
        VMC4;
        BARRIER; LGKM0;
        MFMA4(4, av1);
        DS_READ_B(1);
        DS_READ_A4(1, 0, av0);
        // ph3: MFMA m0-3 (t+1); tail: read m4-7 (t+1)
        STAGE_HALF(B, Bs[0][1], col0 + 128, kb2);
        STAGE_HALF(A, As[0][1], row0 + 128, kb2);
        BARRIER; LGKM0;
        MFMA4(0, av0);
        DS_READ_A4(1, 4, av1);
        // ph4: certify tile t+2; MFMA m4-7 (t+1); tail: read B + m0-3 (t+2)
        STAGE_HALF(A, As[1][0], row0, kb3);
        STAGE_HALF(B, Bs[1][0], col0, kb3);
        VMC4;
        BARRIER; LGKM0;
        MFMA4(4, av1);
        if (t + 2 < NT) {
            DS_READ_B(0);
            DS_READ_A4(0, 0, av0);
        }
    }
    asm volatile("s_waitcnt vmcnt(0) lgkmcnt(0)" ::: "memory");

    // ---- epilogue: C/D layout col = lane&15, row = (lane>>4)*4 + reg (shape-determined,
    //      dtype-independent incl. i8). i32 -> f32 exact (|acc| <= 2048).
#pragma unroll
    for (int m = 0; m < 8; ++m) {
        const int grow = row0 + (m >> 2) * 128 + wm * 64 + (m & 3) * 16 + (lane >> 4) * 4;
#pragma unroll
        for (int n = 0; n < 4; ++n) {
            float* cp = C + (size_t)grow * N + col0 + wn * 64 + n * 16 + (lane & 15);
#pragma unroll
            for (int r = 0; r < 4; ++r)
                cp[(size_t)r * N] = (float)acc[m][n][r];
        }
    }
}

// ---------------- correct-but-slow fallback if workspace is tiny ----------------

__global__ void knaive(const float* __restrict__ X, const float* __restrict__ W,
                       const float* __restrict__ gptr, float* __restrict__ out,
                       int N, int K) {
    size_t idx = (size_t)blockIdx.x * blockDim.x + threadIdx.x;
    const int m = (int)(idx / N), n = (int)(idx % N);
    const float g = *gptr;
    const float* xr = X + (size_t)m * K;
    const float* wrow = W + (size_t)n * K;
    float acc = 0.f;
    for (int k = 0; k < K; ++k) {
        float xv = xr[k];
        float xs = (xv > 0.f) ? 1.f : ((xv < 0.f) ? -1.f : 0.f);
        float w = wrow[k];
        float wq = (rintf(fabsf(w) / g) >= 1.f) ? ((w < 0.f) ? -1.f : 1.f) : 0.f;
        acc += xs * wq;
    }
    out[idx] = acc;
}

// ---------------- launch ----------------

extern "C" void kernel_launch(void* const* d_in, const int* in_sizes, int n_in,
                              void* d_out, int out_size, void* d_ws, size_t ws_size,
                              hipStream_t stream) {
    const float* x = (const float*)d_in[0];
    const float* W = (const float*)d_in[1];
    float* out = (float*)d_out;

    const int K = 2048;                 // in_features
    const int N = in_sizes[1] / K;      // out_features = 2048
    const int M = in_sizes[0] / K;      // 4*4096 = 16384
    const int nW = in_sizes[1];

    char* ws = (char*)d_ws;
    double* partials = (double*)ws;                       // 1024 doubles = 8 KB
    float* gamma = (float*)(ws + 8192);
    u8* wq = (u8*)(ws + 16384);
    u8* xq = (u8*)(ws + 16384 + (size_t)N * K);
    const size_t need = 16384 + (size_t)N * K + (size_t)M * K;

    kabs_partial<<<1024, 256, 0, stream>>>(W, partials, nW);
    kgamma<<<1, 256, 0, stream>>>(partials, gamma, nW);

    if (ws_size >= need && (M % 256) == 0 && (N % 256) == 0 && (K % 256) == 0) {
        kquant_w<<<nW / (256 * 4), 256, 0, stream>>>((const float4*)W, (unsigned int*)wq,
                                                     gamma, nW / 4);
        const size_t n16 = (size_t)M * K / 16;
        kquant_x<<<(unsigned)((n16 + 255) / 256), 256, 0, stream>>>(
            (const float4*)x, (uint4*)xq, n16);
        kgemm<<<(M / 256) * (N / 256), 512, 0, stream>>>(xq, wq, out, M, N, K);
    } else {
        knaive<<<(unsigned)((size_t)M * N / 256), 256, 0, stream>>>(x, W, gamma, out, N, K);
    }
}

// Round 13
// 125.722 us; speedup vs baseline: 1.0026x; 1.0026x over previous
//
#include <hip/hip_runtime.h>
#include <hip/hip_bf16.h>

typedef __attribute__((ext_vector_type(4))) int i32x4;
typedef unsigned char u8;

// ---------------- gamma = mean(|W|) + 1e-6, deterministic two-stage ----------------

__global__ void kabs_partial(const float* __restrict__ W, double* __restrict__ part, int n) {
    __shared__ double sd[256];
    const int tid = threadIdx.x;
    double s = 0.0;
    for (int i = blockIdx.x * blockDim.x + tid; i < n; i += gridDim.x * blockDim.x)
        s += (double)fabsf(W[i]);
    sd[tid] = s;
    __syncthreads();
    for (int off = 128; off > 0; off >>= 1) {
        if (tid < off) sd[tid] += sd[tid + off];
        __syncthreads();
    }
    if (tid == 0) part[blockIdx.x] = sd[0];
}

__global__ void kgamma(const double* __restrict__ part, float* __restrict__ gout, int nelem) {
    __shared__ double sd[256];
    const int tid = threadIdx.x;
    double s = part[tid] + part[tid + 256] + part[tid + 512] + part[tid + 768];
    sd[tid] = s;
    __syncthreads();
    for (int off = 128; off > 0; off >>= 1) {
        if (tid < off) sd[tid] += sd[tid + off];
        __syncthreads();
    }
    if (tid == 0) gout[0] = (float)(sd[0] / (double)nelem) + 1e-6f;
}

// ---------------- quantizers: write i8 {-1,0,+1} ----------------

__device__ __forceinline__ unsigned int qw_b(float w, float g) {
    float t = fabsf(w) / g;
    unsigned int u = __float_as_uint(w);
    return (rintf(t) >= 1.0f) ? ((u >> 31) ? 0xFFu : 0x01u) : 0u;
}

__global__ void kquant_w(const float4* __restrict__ W4, unsigned int* __restrict__ Wq,
                         const float* __restrict__ gptr, int n4) {
    int i = blockIdx.x * blockDim.x + threadIdx.x;
    if (i >= n4) return;
    const float g = *gptr;
    float4 w = W4[i];
    Wq[i] = qw_b(w.x, g) | (qw_b(w.y, g) << 8) | (qw_b(w.z, g) << 16) | (qw_b(w.w, g) << 24);
}

__device__ __forceinline__ unsigned int sgn_b(float a) {
    unsigned int u = __float_as_uint(a);
    return (u & 0x7FFFFFFFu) ? ((u >> 31) ? 0xFFu : 0x01u) : 0u;
}
__device__ __forceinline__ unsigned int sgn4(float4 v) {
    return sgn_b(v.x) | (sgn_b(v.y) << 8) | (sgn_b(v.z) << 16) | (sgn_b(v.w) << 24);
}

__global__ void kquant_x(const float4* __restrict__ X4, uint4* __restrict__ Xq, size_t n16) {
    size_t i = (size_t)blockIdx.x * blockDim.x + threadIdx.x;
    if (i >= n16) return;
    uint4 o;
    o.x = sgn4(X4[4 * i]);
    o.y = sgn4(X4[4 * i + 1]);
    o.z = sgn4(X4[4 * i + 2]);
    o.w = sgn4(X4[4 * i + 3]);
    Xq[i] = o;
}

// ---------------- 256x256 2-phase-per-tile i8 MFMA GEMM, pinned DS/MFMA interleave ------
// C[M][N] = A[M][K] * B[N][K]^T, A/B i8 {-1,0,+1}, acc i32 (exact), out f32.
// Identical calendar/ledger/certify points to the verified R12 kernel (absmax=0).
// ONLY intra-phase instruction ORDER changed: A-frag ds_reads are pinned between
// 8-MFMA chunks via sched_barrier(0) so their LDS drain overlaps the MFMA window
// (R12 profile: 2872 cyc/phase = 1306 MFMA + ~1500 serial LDS drain). B-reads stay
// pinned AFTER the last bv-consuming MFMA (single bv buffer, WAR-safe, no extra VGPR;
// frags+acc already ~244/256 regs). Read windows remain inside the same barrier
// intervals as R12, so the R12 stage-vs-read race audit carries over unchanged.
// ph4's cross-pair reads are unconditional: they read clamped-but-certified data that
// the loop never consumes (uniform, divergence-free).

#define STAGE_HALF(SRC, DST, BASE_ROW, KB)                                                  \
    {                                                                                       \
        _Pragma("unroll")                                                                   \
        for (int l = 0; l < 2; ++l) {                                                       \
            const int r_ = l * 64 + srow;                                                   \
            const u8* g_ = (SRC) + (size_t)((BASE_ROW) + r_) * K + (KB) +                   \
                           (sec ^ ((r_ & 7) << 4));                                         \
            __builtin_amdgcn_global_load_lds(                                               \
                (const __attribute__((address_space(1))) unsigned int*)g_,                  \
                (__attribute__((address_space(3))) unsigned int*)&(DST)[r_][sec], 16, 0, 0);\
        }                                                                                   \
    }

#define BARRIER do { asm volatile("" ::: "memory"); __builtin_amdgcn_s_barrier(); \
                     asm volatile("" ::: "memory"); } while (0)
#define LGKM0   do { asm volatile("s_waitcnt lgkmcnt(0)" ::: "memory"); \
                     __builtin_amdgcn_sched_barrier(0); } while (0)
#define VMC4    asm volatile("s_waitcnt vmcnt(4)" ::: "memory")
#define SB      __builtin_amdgcn_sched_barrier(0)

#define DS_READ_A2(BUF, M0, D0, D1)                                                         \
    {                                                                                       \
        const int ra0 = wm * 64 + ((M0) & 3) * 16 + lr;                                     \
        const int ra1 = wm * 64 + (((M0) + 1) & 3) * 16 + lr;                               \
        _Pragma("unroll")                                                                   \
        for (int ks = 0; ks < 2; ++ks) {                                                    \
            D0[ks] = *(const i32x4*)&As[BUF][(M0) >> 2][ra0]                                \
                         [(ks * 64 + lk16) ^ ((ra0 & 7) << 4)];                             \
            D1[ks] = *(const i32x4*)&As[BUF][((M0) + 1) >> 2][ra1]                          \
                         [(ks * 64 + lk16) ^ ((ra1 & 7) << 4)];                             \
        }                                                                                   \
    }

#define DS_READ_A4(BUF, mb, dst)                                                            \
    {                                                                                       \
        _Pragma("unroll")                                                                   \
        for (int mi = 0; mi < 4; ++mi) {                                                    \
            const int m_ = (mb) + mi;                                                       \
            const int ra = wm * 64 + (m_ & 3) * 16 + lr;                                    \
            _Pragma("unroll")                                                               \
            for (int ks = 0; ks < 2; ++ks)                                                  \
                dst[mi][ks] = *(const i32x4*)&As[BUF][m_ >> 2][ra]                          \
                                  [(ks * 64 + lk16) ^ ((ra & 7) << 4)];                     \
        }                                                                                   \
    }

#define DS_READ_B(BUF)                                                                      \
    {                                                                                       \
        _Pragma("unroll")                                                                   \
        for (int n = 0; n < 4; ++n) {                                                       \
            const int rb = (wn & 1) * 64 + n * 16 + lr;                                     \
            _Pragma("unroll")                                                               \
            for (int ks = 0; ks < 2; ++ks)                                                  \
                bv[n][ks] = *(const i32x4*)&Bs[BUF][wn >> 1][rb]                            \
                                [(ks * 64 + lk16) ^ ((rb & 7) << 4)];                       \
        }                                                                                   \
    }

// 8 independent MFMAs: two m-rows x 4 n at one ks
#define MFMA8(C0, C1, AV, I0, I1, KS)                                                       \
    do {                                                                                    \
        _Pragma("unroll")                                                                   \
        for (int n = 0; n < 4; ++n)                                                         \
            acc[C0][n] = __builtin_amdgcn_mfma_i32_16x16x64_i8(                             \
                AV[I0][KS], bv[n][KS], acc[C0][n], 0, 0, 0);                                \
        _Pragma("unroll")                                                                   \
        for (int n = 0; n < 4; ++n)                                                         \
            acc[C1][n] = __builtin_amdgcn_mfma_i32_16x16x64_i8(                             \
                AV[I1][KS], bv[n][KS], acc[C1][n], 0, 0, 0);                                \
    } while (0)

// odd phase: MFMA m0-3 (AVC) over current bv; interleave reads of m4-7 (BUF) into AVN
#define PH_ODD(BUF, AVC, AVN)                                                               \
    do {                                                                                    \
        __builtin_amdgcn_s_setprio(1);                                                      \
        MFMA8(0, 1, AVC, 0, 1, 0); SB;                                                      \
        DS_READ_A2(BUF, 4, AVN[0], AVN[1]); SB;                                             \
        MFMA8(2, 3, AVC, 2, 3, 0); SB;                                                      \
        DS_READ_A2(BUF, 6, AVN[2], AVN[3]); SB;                                             \
        MFMA8(0, 1, AVC, 0, 1, 1); SB;                                                      \
        MFMA8(2, 3, AVC, 2, 3, 1);                                                          \
        __builtin_amdgcn_s_setprio(0);                                                      \
    } while (0)

// even phase: MFMA m4-7 (AVC); interleave reads of next tile's m0-3 (BUFN) into AVN;
// B reads pinned after the last bv-consuming MFMA (WAR-safe, single bv buffer)
#define PH_EVEN(BUFN, AVC, AVN)                                                             \
    do {                                                                                    \
        __builtin_amdgcn_s_setprio(1);                                                      \
        MFMA8(4, 5, AVC, 0, 1, 0); SB;                                                      \
        DS_READ_A2(BUFN, 0, AVN[0], AVN[1]); SB;                                            \
        MFMA8(6, 7, AVC, 2, 3, 0); SB;                                                      \
        DS_READ_A2(BUFN, 2, AVN[2], AVN[3]); SB;                                            \
        MFMA8(4, 5, AVC, 0, 1, 1); SB;                                                      \
        MFMA8(6, 7, AVC, 2, 3, 1); SB;                                                      \
        DS_READ_B(BUFN);                                                                    \
        __builtin_amdgcn_s_setprio(0);                                                      \
    } while (0)

__global__ __launch_bounds__(512, 2) void kgemm(const u8* __restrict__ A,
                                                const u8* __restrict__ B,
                                                float* __restrict__ C,
                                                int M, int N, int K) {
    __shared__ u8 As[2][2][128][128];
    __shared__ u8 Bs[2][2][128][128];

    const int tid = threadIdx.x;
    const int lane = tid & 63;
    const int wid = tid >> 6;      // 0..7
    const int wm = wid >> 2;       // 0..1  (M sub-block within each half)
    const int wn = wid & 3;        // 0..3  (N sub-block)

    // T1: XCD-aware block swizzle (grid % 8 == 0 here)
    int bid = blockIdx.x;
    const int nwg = gridDim.x;
    if ((nwg & 7) == 0) bid = (bid & 7) * (nwg >> 3) + (bid >> 3);
    const int nbn = N >> 8;
    const int bm = bid / nbn, bn = bid % nbn;
    const int row0 = bm << 8, col0 = bn << 8;

    const int lr = lane & 15;
    const int lk16 = (lane >> 4) * 16;   // byte offset of this lane-group's K-chunk

    // staging thread mapping: 512 threads cover 64 rows x 128 bytes per load instr
    const int srow = tid >> 3;           // 0..63
    const int sec  = (tid & 7) * 16;     // 16-byte chunk within the 128B row

    i32x4 acc[8][4] = {};
    const int NT = K >> 7;               // 16 tiles of K=128 (K % 256 == 0 guaranteed)

    // ---- prologue: tile0 (4 halves) + tile1's {As10,Bs10}; certify tile0; preload frags
    STAGE_HALF(B, Bs[0][0], col0, 0);
    STAGE_HALF(B, Bs[0][1], col0 + 128, 0);
    STAGE_HALF(A, As[0][0], row0, 0);
    STAGE_HALF(A, As[0][1], row0 + 128, 0);
    STAGE_HALF(A, As[1][0], row0, 128);
    STAGE_HALF(B, Bs[1][0], col0, 128);
    VMC4;                                 // drain tile0's 8, leave tile1's 4 in flight
    BARRIER;

    i32x4 bv[4][2], av0[4][2], av1[4][2];
    DS_READ_B(0);
    DS_READ_A4(0, 0, av0);

    for (int t = 0; t < NT; t += 2) {
        const int kb1 = (t + 1) << 7;
        const int kb2 = (t + 2 < NT ? t + 2 : NT - 1) << 7;
        const int kb3 = (t + 3 < NT ? t + 3 : NT - 1) << 7;

        // ph1: complete tile t+1 staging; MFMA m0-3 (t) || read m4-7 (t)
        STAGE_HALF(A, As[1][1], row0 + 128, kb1);
        STAGE_HALF(B, Bs[1][1], col0 + 128, kb1);
        BARRIER; LGKM0;
        PH_ODD(0, av0, av1);
        // ph2: certify tile t+1; MFMA m4-7 (t) || read m0-3 (t+1); B(t+1) trailing
        STAGE_HALF(A, As[0][0], row0, kb2);
        STAGE_HALF(B, Bs[0][0], col0, kb2);
        VMC4;
        BARRIER; LGKM0;
        PH_EVEN(1, av1, av0);
        // ph3: MFMA m0-3 (t+1) || read m4-7 (t+1)
        STAGE_HALF(B, Bs[0][1], col0 + 128, kb2);
        STAGE_HALF(A, As[0][1], row0 + 128, kb2);
        BARRIER; LGKM0;
        PH_ODD(1, av0, av1);
        // ph4: certify tile t+2; MFMA m4-7 (t+1) || read m0-3 (t+2); B(t+2) trailing
        STAGE_HALF(A, As[1][0], row0, kb3);
        STAGE_HALF(B, Bs[1][0], col0, kb3);
        VMC4;
        BARRIER; LGKM0;
        PH_EVEN(0, av1, av0);
    }
    asm volatile("s_waitcnt vmcnt(0) lgkmcnt(0)" ::: "memory");

    // ---- epilogue: C/D layout col = lane&15, row = (lane>>4)*4 + reg (shape-determined,
    //      dtype-independent incl. i8). i32 -> f32 exact (|acc| <= 2048).
#pragma unroll
    for (int m = 0; m < 8; ++m) {
        const int grow = row0 + (m >> 2) * 128 + wm * 64 + (m & 3) * 16 + (lane >> 4) * 4;
#pragma unroll
        for (int n = 0; n < 4; ++n) {
            float* cp = C + (size_t)grow * N + col0 + wn * 64 + n * 16 + (lane & 15);
#pragma unroll
            for (int r = 0; r < 4; ++r)
                cp[(size_t)r * N] = (float)acc[m][n][r];
        }
    }
}

// ---------------- correct-but-slow fallback if workspace is tiny ----------------

__global__ void knaive(const float* __restrict__ X, const float* __restrict__ W,
                       const float* __restrict__ gptr, float* __restrict__ out,
                       int N, int K) {
    size_t idx = (size_t)blockIdx.x * blockDim.x + threadIdx.x;
    const int m = (int)(idx / N), n = (int)(idx % N);
    const float g = *gptr;
    const float* xr = X + (size_t)m * K;
    const float* wrow = W + (size_t)n * K;
    float acc = 0.f;
    for (int k = 0; k < K; ++k) {
        float xv = xr[k];
        float xs = (xv > 0.f) ? 1.f : ((xv < 0.f) ? -1.f : 0.f);
        float w = wrow[k];
        float wq = (rintf(fabsf(w) / g) >= 1.f) ? ((w < 0.f) ? -1.f : 1.f) : 0.f;
        acc += xs * wq;
    }
    out[idx] = acc;
}

// ---------------- launch ----------------

extern "C" void kernel_launch(void* const* d_in, const int* in_sizes, int n_in,
                              void* d_out, int out_size, void* d_ws, size_t ws_size,
                              hipStream_t stream) {
    const float* x = (const float*)d_in[0];
    const float* W = (const float*)d_in[1];
    float* out = (float*)d_out;

    const int K = 2048;                 // in_features
    const int N = in_sizes[1] / K;      // out_features = 2048
    const int M = in_sizes[0] / K;      // 4*4096 = 16384
    const int nW = in_sizes[1];

    char* ws = (char*)d_ws;
    double* partials = (double*)ws;                       // 1024 doubles = 8 KB
    float* gamma = (float*)(ws + 8192);
    u8* wq = (u8*)(ws + 16384);
    u8* xq = (u8*)(ws + 16384 + (size_t)N * K);
    const size_t need = 16384 + (size_t)N * K + (size_t)M * K;

    kabs_partial<<<1024, 256, 0, stream>>>(W, partials, nW);
    kgamma<<<1, 256, 0, stream>>>(partials, gamma, nW);

    if (ws_size >= need && (M % 256) == 0 && (N % 256) == 0 && (K % 256) == 0) {
        kquant_w<<<nW / (256 * 4), 256, 0, stream>>>((const float4*)W, (unsigned int*)wq,
                                                     gamma, nW / 4);
        const size_t n16 = (size_t)M * K / 16;
        kquant_x<<<(unsigned)((n16 + 255) / 256), 256, 0, stream>>>(
            (const float4*)x, (uint4*)xq, n16);
        kgemm<<<(M / 256) * (N / 256), 512, 0, stream>>>(xq, wq, out, M, N, K);
    } else {
        knaive<<<(unsigned)((size_t)M * N / 256), 256, 0, stream>>>(x, W, gamma, out, N, K);
    }
}